// Round 4
// baseline (866.659 us; speedup 1.0000x reference)
//
#include <hip/hip_runtime.h>
#include <hip/hip_bf16.h>
#include <math.h>

#define NEG_SLOPE 0.2f
#define BN_EPS 1e-5f

// ---- bf16 helpers (raw ushort payload) ------------------------------------
__device__ __forceinline__ float bf2f(unsigned short u) {
  union { unsigned int i; float f; } v;
  v.i = ((unsigned int)u) << 16;
  return v.f;
}
__device__ __forceinline__ unsigned short f2bf(float f) {
  union { unsigned int i; float f; } v;
  v.f = f;
  unsigned int i = v.i;
  unsigned int r = (i + 0x7fffu + ((i >> 16) & 1u)) >> 16;  // RNE
  return (unsigned short)r;
}

// ---------------------------------------------------------------------------
// Dtype detection (device-side, deterministic, every call).
// flags[0]=1 if float tensors are bf16, 0 if fp32.
// flags[1]=1 if edge_index is int64, 0 if int32.
// ---------------------------------------------------------------------------
__global__ __launch_bounds__(256) void detect_kernel(
    const unsigned int* __restrict__ xw, const unsigned int* __restrict__ eiw,
    int E, int* __restrict__ flags) {
  __shared__ int cnt[2];
  if (threadIdx.x < 2) cnt[threadIdx.x] = 0;
  __syncthreads();
  int t = threadIdx.x;
  // Float probe: bits 7..14 of each word = exponent field of the low-half
  // bf16 element. For bf16-pair data from N(0,1), that exponent is ~always
  // in [100,135]; for fp32 data these bits are random mantissa bits (~14%).
  int inrange = 0;
  for (int i = t; i < 2048; i += 256) {
    unsigned int e = (xw[i] >> 7) & 0xFFu;
    inrange += (e >= 100u && e <= 135u) ? 1 : 0;
  }
  atomicAdd(&cnt[0], inrange);
  // Index probe: odd int32 words all-zero <=> int64 ids < 2^31.
  int M = min(1024, E / 2);
  int zeros = 0;
  for (int i = t; i < M; i += 256) zeros += (eiw[2 * i + 1] == 0u) ? 1 : 0;
  atomicAdd(&cnt[1], zeros);
  __syncthreads();
  if (t == 0) {
    flags[0] = (cnt[0] > 1536) ? 1 : 0;
    flags[1] = (cnt[1] > M / 2) ? 1 : 0;
  }
}

// Canonicalize a float tensor to bf16 (copy-through if already bf16).
__global__ __launch_bounds__(256) void canon_float(
    const void* __restrict__ src, unsigned short* __restrict__ dst, int n,
    const int* __restrict__ flags) {
  int i = blockIdx.x * 256 + threadIdx.x;
  if (i >= n) return;
  if (flags[0]) dst[i] = ((const unsigned short*)src)[i];
  else dst[i] = f2bf(((const float*)src)[i]);
}

// Canonicalize edge_index to int32 src[]/dst[] arrays.
__global__ __launch_bounds__(256) void canon_idx(
    const int* __restrict__ ei, int* __restrict__ eis, int* __restrict__ eid,
    int E, const int* __restrict__ flags) {
  int e = blockIdx.x * 256 + threadIdx.x;
  if (e >= E) return;
  if (flags[1]) {
    eis[e] = ei[2 * (size_t)e];
    eid[e] = ei[2 * (size_t)E + 2 * (size_t)e];
  } else {
    eis[e] = ei[e];
    eid[e] = ei[E + e];
  }
}

// ---------------------------------------------------------------------------
// GEMM: C[M,N] = A[M,K] @ B[K,N]; A,B bf16 row-major; C bf16 or fp32.
// 64x64 tile, BK=16, 256 threads, 4x4 micro-tile. N,K multiples of 64/16.
// ---------------------------------------------------------------------------
template <bool OUT_BF16>
__global__ __launch_bounds__(256) void gemm_bf16(
    const unsigned short* __restrict__ A, const unsigned short* __restrict__ B,
    void* __restrict__ Cv, int M, int N, int K) {
  __shared__ float As[16][68];  // [k][m], padded
  __shared__ float Bs[16][68];  // [k][n], padded

  const int m0 = blockIdx.y * 64;
  const int n0 = blockIdx.x * 64;
  const int tid = threadIdx.x;
  const int tx = tid & 15;   // n direction
  const int ty = tid >> 4;   // m direction

  float acc[4][4] = {};

  for (int k0 = 0; k0 < K; k0 += 16) {
    {
      int idx = tid * 4;
      int row = idx >> 4;
      int col = idx & 15;
      ushort4 a4 = make_ushort4(0, 0, 0, 0);
      if (m0 + row < M)
        a4 = *(const ushort4*)(A + (size_t)(m0 + row) * K + k0 + col);
      As[col + 0][row] = bf2f(a4.x);
      As[col + 1][row] = bf2f(a4.y);
      As[col + 2][row] = bf2f(a4.z);
      As[col + 3][row] = bf2f(a4.w);
    }
    {
      int idx = tid * 4;
      int row = idx >> 6;
      int col = idx & 63;
      ushort4 b4 = *(const ushort4*)(B + (size_t)(k0 + row) * N + n0 + col);
      Bs[row][col + 0] = bf2f(b4.x);
      Bs[row][col + 1] = bf2f(b4.y);
      Bs[row][col + 2] = bf2f(b4.z);
      Bs[row][col + 3] = bf2f(b4.w);
    }
    __syncthreads();

#pragma unroll
    for (int k = 0; k < 16; ++k) {
      float4 a4 = *(const float4*)&As[k][ty * 4];
      float4 b4 = *(const float4*)&Bs[k][tx * 4];
      float av[4] = {a4.x, a4.y, a4.z, a4.w};
      float bv[4] = {b4.x, b4.y, b4.z, b4.w};
#pragma unroll
      for (int i = 0; i < 4; ++i)
#pragma unroll
        for (int j = 0; j < 4; ++j)
          acc[i][j] = fmaf(av[i], bv[j], acc[i][j]);
    }
    __syncthreads();
  }

#pragma unroll
  for (int i = 0; i < 4; ++i) {
    int row = m0 + ty * 4 + i;
    if (row >= M) continue;
    if (OUT_BF16) {
      unsigned short* C = (unsigned short*)Cv;
      ushort4 o;
      o.x = f2bf(acc[i][0]);
      o.y = f2bf(acc[i][1]);
      o.z = f2bf(acc[i][2]);
      o.w = f2bf(acc[i][3]);
      *(ushort4*)(C + (size_t)row * N + n0 + tx * 4) = o;
    } else {
      float* C = (float*)Cv;
      *(float4*)(C + (size_t)row * N + n0 + tx * 4) =
          make_float4(acc[i][0], acc[i][1], acc[i][2], acc[i][3]);
    }
  }
}

// ---------------------------------------------------------------------------
// CSR build over dst
// ---------------------------------------------------------------------------
__global__ __launch_bounds__(256) void count_dst(const int* __restrict__ eid,
                                                 int E, int* __restrict__ cnt) {
  int e = blockIdx.x * 256 + threadIdx.x;
  if (e < E) atomicAdd(&cnt[eid[e]], 1);
}

// Single block, 1024 threads. cc holds counts on entry; on exit cc[i] =
// start offset (cursor for scatter), offsets[0..N] complete.
__global__ __launch_bounds__(1024) void scan_offsets(int* __restrict__ cc,
                                                     int* __restrict__ offsets,
                                                     int N) {
  __shared__ int sd[1024];
  int t = threadIdx.x;
  int chunk = (N + 1023) >> 10;
  int b0 = min(t * chunk, N);
  int b1 = min(b0 + chunk, N);
  int s = 0;
  for (int i = b0; i < b1; ++i) s += cc[i];
  sd[t] = s;
  __syncthreads();
  for (int off = 1; off < 1024; off <<= 1) {
    int v = (t >= off) ? sd[t - off] : 0;
    __syncthreads();
    sd[t] += v;
    __syncthreads();
  }
  int run = (t == 0) ? 0 : sd[t - 1];
  for (int i = b0; i < b1; ++i) {
    int c = cc[i];
    offsets[i] = run;
    cc[i] = run;
    run += c;
  }
  if (t == 1023) offsets[N] = sd[1023];
}

__global__ __launch_bounds__(256) void scatter_src(
    const int* __restrict__ eis, const int* __restrict__ eid, int E,
    int* __restrict__ cursor, int* __restrict__ srcs) {
  int e = blockIdx.x * 256 + threadIdx.x;
  if (e >= E) return;
  int pos = atomicAdd(&cursor[eid[e]], 1);
  srcs[pos] = eis[e];
}

// ---------------------------------------------------------------------------
// Scores: s[n,h] = dot(h[n,h,:], a[h,:]). One wave per (n,h); C=128.
// ---------------------------------------------------------------------------
__global__ __launch_bounds__(256) void scores_bf16(
    const unsigned short* __restrict__ hfeat,
    const unsigned short* __restrict__ a_src,
    const unsigned short* __restrict__ a_dst, float* __restrict__ s_src,
    float* __restrict__ s_dst, int N, int H) {
  int w = blockIdx.x * 4 + (threadIdx.x >> 6);
  int lane = threadIdx.x & 63;
  if (w >= N * H) return;
  int n = w / H;
  int hh = w - n * H;

  unsigned int hv =
      *(const unsigned int*)(hfeat + (size_t)n * H * 128 + hh * 128 + lane * 2);
  unsigned int av = *(const unsigned int*)(a_src + hh * 128 + lane * 2);
  unsigned int dv = *(const unsigned int*)(a_dst + hh * 128 + lane * 2);
  float h0 = bf2f(hv & 0xffff), h1 = bf2f(hv >> 16);
  float vs = h0 * bf2f(av & 0xffff) + h1 * bf2f(av >> 16);
  float vd = h0 * bf2f(dv & 0xffff) + h1 * bf2f(dv >> 16);
#pragma unroll
  for (int off = 32; off > 0; off >>= 1) {
    vs += __shfl_down(vs, off, 64);
    vd += __shfl_down(vd, off, 64);
  }
  if (lane == 0) {
    s_src[n * H + hh] = vs;
    s_dst[n * H + hh] = vd;
  }
}

// Layer-2 scores: h2 fp32, H=1.
__global__ __launch_bounds__(256) void scores2_f32(
    const float* __restrict__ h2, const unsigned short* __restrict__ a_src,
    const unsigned short* __restrict__ a_dst, float* __restrict__ s_src,
    float* __restrict__ s_dst, int N) {
  int w = blockIdx.x * 4 + (threadIdx.x >> 6);
  int lane = threadIdx.x & 63;
  if (w >= N) return;
  float2 hv = *(const float2*)(h2 + (size_t)w * 128 + lane * 2);
  unsigned int av = *(const unsigned int*)(a_src + lane * 2);
  unsigned int dv = *(const unsigned int*)(a_dst + lane * 2);
  float vs = hv.x * bf2f(av & 0xffff) + hv.y * bf2f(av >> 16);
  float vd = hv.x * bf2f(dv & 0xffff) + hv.y * bf2f(dv >> 16);
#pragma unroll
  for (int off = 32; off > 0; off >>= 1) {
    vs += __shfl_down(vs, off, 64);
    vd += __shfl_down(vd, off, 64);
  }
  if (lane == 0) {
    s_src[w] = vs;
    s_dst[w] = vd;
  }
}

// ---------------------------------------------------------------------------
// Layer-1 aggregation (CSR, block per dst node, 256 threads, 4 ch/thread).
// Softmax denom in-loop (no max-shift; |e| is O(5), exp can't overflow).
// Epilogue: /denom + b1, write bf16 h1n.
// ---------------------------------------------------------------------------
__global__ __launch_bounds__(256) void agg1_csr(
    const int* __restrict__ offsets, const int* __restrict__ srcs,
    const unsigned short* __restrict__ h1, const float* __restrict__ ssrc,
    const float* __restrict__ sdst, const unsigned short* __restrict__ b1,
    unsigned short* __restrict__ h1n) {
  int n = blockIdx.x;
  int j = threadIdx.x;
  int c = j * 4;
  int h = c >> 7;
  float sd = sdst[n * 8 + h];
  int beg = offsets[n], end = offsets[n + 1];
  float a0 = 0.f, a1 = 0.f, a2 = 0.f, a3 = 0.f, wsum = 0.f;
  for (int p = beg; p < end; ++p) {
    int s = srcs[p];
    float v = ssrc[s * 8 + h] + sd;
    v = v > 0.f ? v : NEG_SLOPE * v;
    float w = expf(v);
    wsum += w;
    ushort4 u = *(const ushort4*)(h1 + (size_t)s * 1024 + c);
    a0 = fmaf(bf2f(u.x), w, a0);
    a1 = fmaf(bf2f(u.y), w, a1);
    a2 = fmaf(bf2f(u.z), w, a2);
    a3 = fmaf(bf2f(u.w), w, a3);
  }
  float inv = 1.0f / (wsum + 1e-16f);
  ushort4 bb = *(const ushort4*)(b1 + c);
  ushort4 o;
  o.x = f2bf(a0 * inv + bf2f(bb.x));
  o.y = f2bf(a1 * inv + bf2f(bb.y));
  o.z = f2bf(a2 * inv + bf2f(bb.z));
  o.w = f2bf(a3 * inv + bf2f(bb.w));
  *(ushort4*)(h1n + (size_t)n * 1024 + c) = o;
}

// ---------------------------------------------------------------------------
// BN partial sums over h1n (bf16).
// ---------------------------------------------------------------------------
__global__ __launch_bounds__(256) void bn_stats(
    const unsigned short* __restrict__ h1n, float* __restrict__ bnsum,
    float* __restrict__ bnsumsq, int N, int rowsPerBlock) {
  int r0 = blockIdx.x * rowsPerBlock;
  int r1 = min(r0 + rowsPerBlock, N);
  int c = threadIdx.x * 4;
  float s0 = 0, s1 = 0, s2 = 0, s3 = 0;
  float q0 = 0, q1 = 0, q2 = 0, q3 = 0;
  for (int r = r0; r < r1; ++r) {
    ushort4 u = *(const ushort4*)(h1n + (size_t)r * 1024 + c);
    float v0 = bf2f(u.x), v1 = bf2f(u.y), v2 = bf2f(u.z), v3 = bf2f(u.w);
    s0 += v0; s1 += v1; s2 += v2; s3 += v3;
    q0 += v0 * v0; q1 += v1 * v1; q2 += v2 * v2; q3 += v3 * v3;
  }
  atomicAdd(&bnsum[c + 0], s0);
  atomicAdd(&bnsum[c + 1], s1);
  atomicAdd(&bnsum[c + 2], s2);
  atomicAdd(&bnsum[c + 3], s3);
  atomicAdd(&bnsumsq[c + 0], q0);
  atomicAdd(&bnsumsq[c + 1], q1);
  atomicAdd(&bnsumsq[c + 2], q2);
  atomicAdd(&bnsumsq[c + 3], q3);
}

__global__ __launch_bounds__(1024) void bn_finalize(
    const float* __restrict__ bnsum, const float* __restrict__ bnsumsq,
    const unsigned short* __restrict__ gamma,
    const unsigned short* __restrict__ beta, float* __restrict__ scale,
    float* __restrict__ shift, int N) {
  int j = threadIdx.x;
  float inv_n = 1.0f / (float)N;
  float mu = bnsum[j] * inv_n;
  float var = bnsumsq[j] * inv_n - mu * mu;
  float sc = bf2f(gamma[j]) * rsqrtf(var + BN_EPS);
  scale[j] = sc;
  shift[j] = bf2f(beta[j]) - mu * sc;
}

// BN apply + ELU in-place on bf16 h1n. One thread = 4 channels.
__global__ __launch_bounds__(256) void bn_apply_elu(
    unsigned short* __restrict__ h1n, const float* __restrict__ scale,
    const float* __restrict__ shift, int total4) {
  int t = blockIdx.x * 256 + threadIdx.x;
  if (t >= total4) return;
  size_t base = (size_t)t * 4;
  int c = (int)(base & 1023);
  ushort4 u = *(const ushort4*)(h1n + base);
  float4 sc = *(const float4*)(scale + c);
  float4 sh = *(const float4*)(shift + c);
  float r0 = bf2f(u.x) * sc.x + sh.x;
  float r1 = bf2f(u.y) * sc.y + sh.y;
  float r2 = bf2f(u.z) * sc.z + sh.z;
  float r3 = bf2f(u.w) * sc.w + sh.w;
  r0 = r0 > 0.f ? r0 : expm1f(r0);
  r1 = r1 > 0.f ? r1 : expm1f(r1);
  r2 = r2 > 0.f ? r2 : expm1f(r2);
  r3 = r3 > 0.f ? r3 : expm1f(r3);
  ushort4 o;
  o.x = f2bf(r0); o.y = f2bf(r1); o.z = f2bf(r2); o.w = f2bf(r3);
  *(ushort4*)(h1n + base) = o;
}

// ---------------------------------------------------------------------------
// Layer-2 aggregation (CSR, one wave per dst, 2 ch/lane). Output dtype
// dispatched on flags[0] (bf16 vs fp32).
// ---------------------------------------------------------------------------
__global__ __launch_bounds__(64) void agg2_csr(
    const int* __restrict__ offsets, const int* __restrict__ srcs,
    const float* __restrict__ h2, const float* __restrict__ ssrc,
    const float* __restrict__ sdst, const unsigned short* __restrict__ b2,
    void* __restrict__ out, const int* __restrict__ flags) {
  int n = blockIdx.x;
  int lane = threadIdx.x;
  int c = lane * 2;
  float sd = sdst[n];
  int beg = offsets[n], end = offsets[n + 1];
  float a0 = 0.f, a1 = 0.f, wsum = 0.f;
  for (int p = beg; p < end; ++p) {
    int s = srcs[p];
    float v = ssrc[s] + sd;
    v = v > 0.f ? v : NEG_SLOPE * v;
    float w = expf(v);
    wsum += w;
    float2 hv = *(const float2*)(h2 + (size_t)s * 128 + c);
    a0 = fmaf(hv.x, w, a0);
    a1 = fmaf(hv.y, w, a1);
  }
  float inv = 1.0f / (wsum + 1e-16f);
  unsigned int bb = *(const unsigned int*)(b2 + c);
  float r0 = a0 * inv + bf2f(bb & 0xffff);
  float r1 = a1 * inv + bf2f(bb >> 16);
  if (flags[0]) {
    unsigned int o =
        (unsigned int)f2bf(r0) | ((unsigned int)f2bf(r1) << 16);
    *(unsigned int*)((unsigned short*)out + (size_t)n * 128 + c) = o;
  } else {
    *(float2*)((float*)out + (size_t)n * 128 + c) = make_float2(r0, r1);
  }
}

// ---------------------------------------------------------------------------
extern "C" void kernel_launch(void* const* d_in, const int* in_sizes, int n_in,
                              void* d_out, int out_size, void* d_ws,
                              size_t ws_size, hipStream_t stream) {
  const void* x      = d_in[0];
  const int*  ei     = (const int*)d_in[1];
  const void* W1     = d_in[2];
  const void* a_src1 = d_in[3];
  const void* a_dst1 = d_in[4];
  const void* b1     = d_in[5];
  const void* gamma  = d_in[6];
  const void* beta   = d_in[7];
  const void* W2     = d_in[8];
  const void* a_src2 = d_in[9];
  const void* a_dst2 = d_in[10];
  const void* b2     = d_in[11];

  const int N = in_sizes[0] / 128;  // 50000
  const int E = in_sizes[1] / 2;    // 150000

  // ---- workspace layout (bytes) ----
  char* ws = (char*)d_ws;
  size_t off = 0;
  unsigned short* h1  = (unsigned short*)(ws + off); off += (size_t)N * 1024 * 2;
  char* h1n_base = ws + off;
  unsigned short* h1n = (unsigned short*)h1n_base;    off += (size_t)N * 1024 * 2;
  float* ssrc1 = (float*)(ws + off); off += (size_t)N * 8 * 4;
  float* sdst1 = (float*)(ws + off); off += (size_t)N * 8 * 4;
  int* offsets = (int*)(ws + off); off += (size_t)(N + 1) * 4;
  int* srcs    = (int*)(ws + off); off += (size_t)E * 4;
  unsigned short* W1c = (unsigned short*)(ws + off); off += 131072 * 2;
  unsigned short* W2c = (unsigned short*)(ws + off); off += 131072 * 2;
  unsigned short* as1c = (unsigned short*)(ws + off); off += 1024 * 2;
  unsigned short* ad1c = (unsigned short*)(ws + off); off += 1024 * 2;
  unsigned short* b1c  = (unsigned short*)(ws + off); off += 1024 * 2;
  unsigned short* gmc  = (unsigned short*)(ws + off); off += 1024 * 2;
  unsigned short* btc  = (unsigned short*)(ws + off); off += 1024 * 2;
  unsigned short* as2c = (unsigned short*)(ws + off); off += 128 * 2;
  unsigned short* ad2c = (unsigned short*)(ws + off); off += 128 * 2;
  unsigned short* b2c  = (unsigned short*)(ws + off); off += 128 * 2;
  float* bns1  = (float*)(ws + off); off += 1024 * 4;
  float* bns2  = (float*)(ws + off); off += 1024 * 4;
  float* scale = (float*)(ws + off); off += 1024 * 4;
  float* shift = (float*)(ws + off); off += 1024 * 4;
  int* flags   = (int*)(ws + off); off += 64;
  // Aliases into dead regions:
  // x_bf/eis/eid/cursor live inside h1n's region (all dead before agg1 writes h1n)
  unsigned short* x_bf = (unsigned short*)h1n_base;             // 12.8 MB
  int* eis    = (int*)(h1n_base + (16u << 20));                 // E*4
  int* eid    = eis + E;                                        // E*4
  int* cursor = eid + E;                                        // N*4
  // h2 (fp32 [N,128]) aliases h1 (dead after agg1)
  float* h2    = (float*)h1;
  float* ssrc2 = ssrc1;
  float* sdst2 = sdst1;

  // ---- detection + canonicalization ----
  detect_kernel<<<1, 256, 0, stream>>>((const unsigned int*)x,
                                       (const unsigned int*)ei, E, flags);
  canon_float<<<(N * 128 + 255) / 256, 256, 0, stream>>>(x, x_bf, N * 128, flags);
  canon_float<<<(131072 + 255) / 256, 256, 0, stream>>>(W1, W1c, 131072, flags);
  canon_float<<<(131072 + 255) / 256, 256, 0, stream>>>(W2, W2c, 131072, flags);
  canon_float<<<4, 256, 0, stream>>>(a_src1, as1c, 1024, flags);
  canon_float<<<4, 256, 0, stream>>>(a_dst1, ad1c, 1024, flags);
  canon_float<<<4, 256, 0, stream>>>(b1, b1c, 1024, flags);
  canon_float<<<4, 256, 0, stream>>>(gamma, gmc, 1024, flags);
  canon_float<<<4, 256, 0, stream>>>(beta, btc, 1024, flags);
  canon_float<<<1, 256, 0, stream>>>(a_src2, as2c, 128, flags);
  canon_float<<<1, 256, 0, stream>>>(a_dst2, ad2c, 128, flags);
  canon_float<<<1, 256, 0, stream>>>(b2, b2c, 128, flags);
  canon_idx<<<(E + 255) / 256, 256, 0, stream>>>(ei, eis, eid, E, flags);

  // ---- CSR build (dst-sorted) ----
  hipMemsetAsync(cursor, 0, (size_t)N * 4, stream);
  hipMemsetAsync(bns1, 0, 2048 * 4, stream);  // bns1+bns2 contiguous
  count_dst<<<(E + 255) / 256, 256, 0, stream>>>(eid, E, cursor);
  scan_offsets<<<1, 1024, 0, stream>>>(cursor, offsets, N);
  scatter_src<<<(E + 255) / 256, 256, 0, stream>>>(eis, eid, E, cursor, srcs);

  // ---- Layer 1 ----
  {
    dim3 g(1024 / 64, (N + 63) / 64);
    gemm_bf16<true><<<g, 256, 0, stream>>>(x_bf, W1c, h1, N, 1024, 128);
  }
  scores_bf16<<<(N * 8 + 3) / 4, 256, 0, stream>>>(h1, as1c, ad1c, ssrc1,
                                                   sdst1, N, 8);
  agg1_csr<<<N, 256, 0, stream>>>(offsets, srcs, h1, ssrc1, sdst1, b1c, h1n);

  bn_stats<<<(N + 255) / 256, 256, 0, stream>>>(h1n, bns1, bns2, N, 256);
  bn_finalize<<<1, 1024, 0, stream>>>(bns1, bns2, gmc, btc, scale, shift, N);
  bn_apply_elu<<<(N * 256 + 255) / 256, 256, 0, stream>>>(h1n, scale, shift,
                                                          N * 256);

  // ---- Layer 2 ----
  {
    dim3 g(128 / 64, (N + 63) / 64);
    gemm_bf16<false><<<g, 256, 0, stream>>>(h1n, W2c, h2, N, 128, 1024);
  }
  scores2_f32<<<(N + 3) / 4, 256, 0, stream>>>(h2, as2c, ad2c, ssrc2, sdst2, N);
  agg2_csr<<<N, 64, 0, stream>>>(offsets, srcs, h2, ssrc2, sdst2, b2c, d_out,
                                 flags);
}

// Round 5
// 617.351 us; speedup vs baseline: 1.4038x; 1.4038x over previous
//
#include <hip/hip_runtime.h>
#include <hip/hip_bf16.h>
#include <math.h>

#define NEG_SLOPE 0.2f
#define BN_EPS 1e-5f

typedef short bf16x8 __attribute__((ext_vector_type(8)));
typedef float f32x4 __attribute__((ext_vector_type(4)));

// ---- bf16 helpers (raw ushort payload) ------------------------------------
__device__ __forceinline__ float bf2f(unsigned short u) {
  union { unsigned int i; float f; } v;
  v.i = ((unsigned int)u) << 16;
  return v.f;
}
__device__ __forceinline__ unsigned short f2bf(float f) {
  union { unsigned int i; float f; } v;
  v.f = f;
  unsigned int i = v.i;
  unsigned int r = (i + 0x7fffu + ((i >> 16) & 1u)) >> 16;  // RNE
  return (unsigned short)r;
}

// ---------------------------------------------------------------------------
// Dtype detection: flags[0]=1 if floats are bf16; flags[1]=1 if idx int64.
// ---------------------------------------------------------------------------
__global__ __launch_bounds__(256) void detect_kernel(
    const unsigned int* __restrict__ xw, const unsigned int* __restrict__ eiw,
    int E, int* __restrict__ flags) {
  __shared__ int cnt[2];
  if (threadIdx.x < 2) cnt[threadIdx.x] = 0;
  __syncthreads();
  int t = threadIdx.x;
  int inrange = 0;
  for (int i = t; i < 2048; i += 256) {
    unsigned int e = (xw[i] >> 7) & 0xFFu;
    inrange += (e >= 100u && e <= 135u) ? 1 : 0;
  }
  atomicAdd(&cnt[0], inrange);
  int M = min(1024, E / 2);
  int zeros = 0;
  for (int i = t; i < M; i += 256) zeros += (eiw[2 * i + 1] == 0u) ? 1 : 0;
  atomicAdd(&cnt[1], zeros);
  __syncthreads();
  if (t == 0) {
    flags[0] = (cnt[0] > 1536) ? 1 : 0;
    flags[1] = (cnt[1] > M / 2) ? 1 : 0;
  }
}

// x -> bf16, zero-padded to n_total elements.
__global__ __launch_bounds__(256) void canon_x(
    const void* __restrict__ src, unsigned short* __restrict__ dst, int n_real,
    int n_total, const int* __restrict__ flags) {
  int i = blockIdx.x * 256 + threadIdx.x;
  if (i >= n_total) return;
  unsigned short v = 0;
  if (i < n_real)
    v = flags[0] ? ((const unsigned short*)src)[i]
                 : f2bf(((const float*)src)[i]);
  dst[i] = v;
}

// W [K][N] -> Wt [N][K] bf16.
__global__ __launch_bounds__(256) void canon_w_t(
    const void* __restrict__ src, unsigned short* __restrict__ dst, int Kdim,
    int Ndim, const int* __restrict__ flags) {
  int i = blockIdx.x * 256 + threadIdx.x;
  if (i >= Kdim * Ndim) return;
  int k = i / Ndim, n = i - k * Ndim;
  unsigned short v = flags[0] ? ((const unsigned short*)src)[i]
                              : f2bf(((const float*)src)[i]);
  dst[(size_t)n * Kdim + k] = v;
}

// All small param tensors in one launch: block b -> tensor b.
__global__ __launch_bounds__(1024) void canon_params(
    const void* s0, const void* s1, const void* s2, const void* s3,
    const void* s4, const void* s5, const void* s6, const void* s7,
    unsigned short* d0, unsigned short* d1, unsigned short* d2,
    unsigned short* d3, unsigned short* d4, unsigned short* d5,
    unsigned short* d6, unsigned short* d7, const int* __restrict__ flags) {
  int b = blockIdx.x, t = threadIdx.x;
  const void* s;
  unsigned short* d;
  int n;
  switch (b) {
    case 0: s = s0; d = d0; n = 1024; break;
    case 1: s = s1; d = d1; n = 1024; break;
    case 2: s = s2; d = d2; n = 1024; break;
    case 3: s = s3; d = d3; n = 1024; break;
    case 4: s = s4; d = d4; n = 1024; break;
    case 5: s = s5; d = d5; n = 128; break;
    case 6: s = s6; d = d6; n = 128; break;
    default: s = s7; d = d7; n = 128; break;
  }
  if (t < n)
    d[t] = flags[0] ? ((const unsigned short*)s)[t]
                    : f2bf(((const float*)s)[t]);
}

// edge_index -> int32 src[]/dst[].
__global__ __launch_bounds__(256) void canon_idx(
    const int* __restrict__ ei, int* __restrict__ eis, int* __restrict__ eid,
    int E, const int* __restrict__ flags) {
  int e = blockIdx.x * 256 + threadIdx.x;
  if (e >= E) return;
  if (flags[1]) {
    eis[e] = ei[2 * (size_t)e];
    eid[e] = ei[2 * (size_t)E + 2 * (size_t)e];
  } else {
    eis[e] = ei[e];
    eid[e] = ei[E + e];
  }
}

// ---------------------------------------------------------------------------
// MFMA GEMM: C[M,BNgrid*128] = A[M,K] @ Bt[N,K]^T.  A,Bt bf16 row-major.
// BM in {64,128}, BN=128, BK=32, 256 threads = 4 waves (2x2), wave tile
// (BM/2)x64 of 16x16x32 MFMAs.  M must be a multiple of BM (padded buffers).
// TRANSFORM_A: A' = ELU(A*scale[ch]+shift[ch]) applied during staging
// (fuses BatchNorm+ELU into GEMM2's A-load).
// Fragment maps (verified m89/m91): A[m=lane&15][k=(lane>>4)*8+j],
// B[k=(lane>>4)*8+j][n=lane&15], C/D[row=(lane>>4)*4+i][col=lane&15].
// ---------------------------------------------------------------------------
template <int BM, bool TRANSFORM_A, bool OUT_BF16>
__global__ __launch_bounds__(256) void gemm_mfma(
    const unsigned short* __restrict__ A, const unsigned short* __restrict__ Bt,
    void* __restrict__ Cv, int M, int N, int K,
    const float* __restrict__ scale, const float* __restrict__ shift) {
  constexpr int BK = 32;
  constexpr int LDA = BK + 8;  // pad: frag rows land 2-way max (free, m136)
  __shared__ unsigned short As[BM * LDA];
  __shared__ unsigned short Bs[128 * LDA];

  const int m0 = blockIdx.y * BM;
  const int n0 = blockIdx.x * 128;
  const int tid = threadIdx.x;
  const int wid = tid >> 6;
  const int lane = tid & 63;
  const int q = lane >> 4;
  const int r = lane & 15;
  const int wm = (wid >> 1) * (BM / 2);
  const int wn = (wid & 1) * 64;

  constexpr int MI = BM / 32;  // 16-row tiles per wave
  f32x4 acc[MI][4] = {};

  for (int k0 = 0; k0 < K; k0 += BK) {
    // Stage A (BM x 32): thread loads bf16x8; 2048 elems per 256-thread round.
#pragma unroll
    for (int rd = 0; rd < BM / 64; ++rd) {
      int idx = rd * 2048 + tid * 8;
      int row = idx >> 5;
      int col = idx & 31;
      bf16x8 v = *(const bf16x8*)(A + (size_t)(m0 + row) * K + k0 + col);
      if (TRANSFORM_A) {
        union { bf16x8 v; unsigned short u[8]; } p;
        p.v = v;
#pragma unroll
        for (int j = 0; j < 8; ++j) {
          int ch = k0 + col + j;
          float f = bf2f(p.u[j]) * scale[ch] + shift[ch];
          f = f > 0.f ? f : expm1f(f);
          p.u[j] = f2bf(f);
        }
        v = p.v;
      }
      *(bf16x8*)(&As[row * LDA + col]) = v;
    }
    // Stage B (128 x 32) from Bt rows (identical pattern).
#pragma unroll
    for (int rd = 0; rd < 2; ++rd) {
      int idx = rd * 2048 + tid * 8;
      int row = idx >> 5;
      int col = idx & 31;
      bf16x8 v = *(const bf16x8*)(Bt + (size_t)(n0 + row) * K + k0 + col);
      *(bf16x8*)(&Bs[row * LDA + col]) = v;
    }
    __syncthreads();

    bf16x8 af[MI], bfv[4];
#pragma unroll
    for (int mi = 0; mi < MI; ++mi)
      af[mi] = *(const bf16x8*)(&As[(wm + mi * 16 + r) * LDA + q * 8]);
#pragma unroll
    for (int ni = 0; ni < 4; ++ni)
      bfv[ni] = *(const bf16x8*)(&Bs[(wn + ni * 16 + r) * LDA + q * 8]);
#pragma unroll
    for (int mi = 0; mi < MI; ++mi)
#pragma unroll
      for (int ni = 0; ni < 4; ++ni)
        acc[mi][ni] = __builtin_amdgcn_mfma_f32_16x16x32_bf16(
            af[mi], bfv[ni], acc[mi][ni], 0, 0, 0);
    __syncthreads();
  }

#pragma unroll
  for (int mi = 0; mi < MI; ++mi) {
#pragma unroll
    for (int ni = 0; ni < 4; ++ni) {
#pragma unroll
      for (int i = 0; i < 4; ++i) {
        int row = m0 + wm + mi * 16 + q * 4 + i;
        int col = n0 + wn + ni * 16 + r;
        if (OUT_BF16)
          ((unsigned short*)Cv)[(size_t)row * N + col] = f2bf(acc[mi][ni][i]);
        else
          ((float*)Cv)[(size_t)row * N + col] = acc[mi][ni][i];
      }
    }
  }
}

// ---------------------------------------------------------------------------
// CSR build over dst
// ---------------------------------------------------------------------------
__global__ __launch_bounds__(256) void count_dst(const int* __restrict__ eid,
                                                 int E, int* __restrict__ cnt) {
  int e = blockIdx.x * 256 + threadIdx.x;
  if (e < E) atomicAdd(&cnt[eid[e]], 1);
}

__global__ __launch_bounds__(1024) void scan_offsets(int* __restrict__ cc,
                                                     int* __restrict__ offsets,
                                                     int N) {
  __shared__ int sd[1024];
  int t = threadIdx.x;
  int chunk = (N + 1023) >> 10;
  int b0 = min(t * chunk, N);
  int b1 = min(b0 + chunk, N);
  int s = 0;
  for (int i = b0; i < b1; ++i) s += cc[i];
  sd[t] = s;
  __syncthreads();
  for (int off = 1; off < 1024; off <<= 1) {
    int v = (t >= off) ? sd[t - off] : 0;
    __syncthreads();
    sd[t] += v;
    __syncthreads();
  }
  int run = (t == 0) ? 0 : sd[t - 1];
  for (int i = b0; i < b1; ++i) {
    int c = cc[i];
    offsets[i] = run;
    cc[i] = run;
    run += c;
  }
  if (t == 1023) offsets[N] = sd[1023];
}

__global__ __launch_bounds__(256) void scatter_src(
    const int* __restrict__ eis, const int* __restrict__ eid, int E,
    int* __restrict__ cursor, int* __restrict__ srcs) {
  int e = blockIdx.x * 256 + threadIdx.x;
  if (e >= E) return;
  int pos = atomicAdd(&cursor[eid[e]], 1);
  srcs[pos] = eis[e];
}

// ---------------------------------------------------------------------------
// Scores: s[n,h] = dot(h[n,h,:], a[h,:]). One wave per (n,h); C=128.
// ---------------------------------------------------------------------------
__global__ __launch_bounds__(256) void scores_bf16(
    const unsigned short* __restrict__ hfeat,
    const unsigned short* __restrict__ a_src,
    const unsigned short* __restrict__ a_dst, float* __restrict__ s_src,
    float* __restrict__ s_dst, int N, int H) {
  int w = blockIdx.x * 4 + (threadIdx.x >> 6);
  int lane = threadIdx.x & 63;
  if (w >= N * H) return;
  int n = w / H;
  int hh = w - n * H;

  unsigned int hv =
      *(const unsigned int*)(hfeat + (size_t)n * H * 128 + hh * 128 + lane * 2);
  unsigned int av = *(const unsigned int*)(a_src + hh * 128 + lane * 2);
  unsigned int dv = *(const unsigned int*)(a_dst + hh * 128 + lane * 2);
  float h0 = bf2f(hv & 0xffff), h1 = bf2f(hv >> 16);
  float vs = h0 * bf2f(av & 0xffff) + h1 * bf2f(av >> 16);
  float vd = h0 * bf2f(dv & 0xffff) + h1 * bf2f(dv >> 16);
#pragma unroll
  for (int off = 32; off > 0; off >>= 1) {
    vs += __shfl_down(vs, off, 64);
    vd += __shfl_down(vd, off, 64);
  }
  if (lane == 0) {
    s_src[n * H + hh] = vs;
    s_dst[n * H + hh] = vd;
  }
}

// Layer-2 scores: h2 fp32, H=1.
__global__ __launch_bounds__(256) void scores2_f32(
    const float* __restrict__ h2, const unsigned short* __restrict__ a_src,
    const unsigned short* __restrict__ a_dst, float* __restrict__ s_src,
    float* __restrict__ s_dst, int N) {
  int w = blockIdx.x * 4 + (threadIdx.x >> 6);
  int lane = threadIdx.x & 63;
  if (w >= N) return;
  float2 hv = *(const float2*)(h2 + (size_t)w * 128 + lane * 2);
  unsigned int av = *(const unsigned int*)(a_src + lane * 2);
  unsigned int dv = *(const unsigned int*)(a_dst + lane * 2);
  float vs = hv.x * bf2f(av & 0xffff) + hv.y * bf2f(av >> 16);
  float vd = hv.x * bf2f(dv & 0xffff) + hv.y * bf2f(dv >> 16);
#pragma unroll
  for (int off = 32; off > 0; off >>= 1) {
    vs += __shfl_down(vs, off, 64);
    vd += __shfl_down(vd, off, 64);
  }
  if (lane == 0) {
    s_src[w] = vs;
    s_dst[w] = vd;
  }
}

// ---------------------------------------------------------------------------
// Layer-1 aggregation (CSR, block per dst node, 256 threads, 4 ch/thread).
// Writes h1n = raw agg/denom + b1 (pre-BN, bf16). BN+ELU applied in GEMM2.
// ---------------------------------------------------------------------------
__global__ __launch_bounds__(256) void agg1_csr(
    const int* __restrict__ offsets, const int* __restrict__ srcs,
    const unsigned short* __restrict__ h1, const float* __restrict__ ssrc,
    const float* __restrict__ sdst, const unsigned short* __restrict__ b1,
    unsigned short* __restrict__ h1n) {
  int n = blockIdx.x;
  int j = threadIdx.x;
  int c = j * 4;
  int h = c >> 7;
  float sd = sdst[n * 8 + h];
  int beg = offsets[n], end = offsets[n + 1];
  float a0 = 0.f, a1 = 0.f, a2 = 0.f, a3 = 0.f, wsum = 0.f;
  for (int p = beg; p < end; ++p) {
    int s = srcs[p];
    float v = ssrc[s * 8 + h] + sd;
    v = v > 0.f ? v : NEG_SLOPE * v;
    float w = expf(v);
    wsum += w;
    ushort4 u = *(const ushort4*)(h1 + (size_t)s * 1024 + c);
    a0 = fmaf(bf2f(u.x), w, a0);
    a1 = fmaf(bf2f(u.y), w, a1);
    a2 = fmaf(bf2f(u.z), w, a2);
    a3 = fmaf(bf2f(u.w), w, a3);
  }
  float inv = 1.0f / (wsum + 1e-16f);
  ushort4 bb = *(const ushort4*)(b1 + c);
  ushort4 o;
  o.x = f2bf(a0 * inv + bf2f(bb.x));
  o.y = f2bf(a1 * inv + bf2f(bb.y));
  o.z = f2bf(a2 * inv + bf2f(bb.z));
  o.w = f2bf(a3 * inv + bf2f(bb.w));
  *(ushort4*)(h1n + (size_t)n * 1024 + c) = o;
}

// ---------------------------------------------------------------------------
// BN partial sums over h1n (bf16, pre-BN values).
// ---------------------------------------------------------------------------
__global__ __launch_bounds__(256) void bn_stats(
    const unsigned short* __restrict__ h1n, float* __restrict__ bnsum,
    float* __restrict__ bnsumsq, int N, int rowsPerBlock) {
  int r0 = blockIdx.x * rowsPerBlock;
  int r1 = min(r0 + rowsPerBlock, N);
  int c = threadIdx.x * 4;
  float s0 = 0, s1 = 0, s2 = 0, s3 = 0;
  float q0 = 0, q1 = 0, q2 = 0, q3 = 0;
  for (int r = r0; r < r1; ++r) {
    ushort4 u = *(const ushort4*)(h1n + (size_t)r * 1024 + c);
    float v0 = bf2f(u.x), v1 = bf2f(u.y), v2 = bf2f(u.z), v3 = bf2f(u.w);
    s0 += v0; s1 += v1; s2 += v2; s3 += v3;
    q0 += v0 * v0; q1 += v1 * v1; q2 += v2 * v2; q3 += v3 * v3;
  }
  atomicAdd(&bnsum[c + 0], s0);
  atomicAdd(&bnsum[c + 1], s1);
  atomicAdd(&bnsum[c + 2], s2);
  atomicAdd(&bnsum[c + 3], s3);
  atomicAdd(&bnsumsq[c + 0], q0);
  atomicAdd(&bnsumsq[c + 1], q1);
  atomicAdd(&bnsumsq[c + 2], q2);
  atomicAdd(&bnsumsq[c + 3], q3);
}

__global__ __launch_bounds__(1024) void bn_finalize(
    const float* __restrict__ bnsum, const float* __restrict__ bnsumsq,
    const unsigned short* __restrict__ gamma,
    const unsigned short* __restrict__ beta, float* __restrict__ scale,
    float* __restrict__ shift, int N) {
  int j = threadIdx.x;
  float inv_n = 1.0f / (float)N;
  float mu = bnsum[j] * inv_n;
  float var = bnsumsq[j] * inv_n - mu * mu;
  float sc = bf2f(gamma[j]) * rsqrtf(var + BN_EPS);
  scale[j] = sc;
  shift[j] = bf2f(beta[j]) - mu * sc;
}

// ---------------------------------------------------------------------------
// Layer-2 aggregation (CSR, one wave per dst, 2 ch/lane). Output dtype
// dispatched on flags[0].
// ---------------------------------------------------------------------------
__global__ __launch_bounds__(64) void agg2_csr(
    const int* __restrict__ offsets, const int* __restrict__ srcs,
    const float* __restrict__ h2, const float* __restrict__ ssrc,
    const float* __restrict__ sdst, const unsigned short* __restrict__ b2,
    void* __restrict__ out, const int* __restrict__ flags) {
  int n = blockIdx.x;
  int lane = threadIdx.x;
  int c = lane * 2;
  float sd = sdst[n];
  int beg = offsets[n], end = offsets[n + 1];
  float a0 = 0.f, a1 = 0.f, wsum = 0.f;
  for (int p = beg; p < end; ++p) {
    int s = srcs[p];
    float v = ssrc[s] + sd;
    v = v > 0.f ? v : NEG_SLOPE * v;
    float w = expf(v);
    wsum += w;
    float2 hv = *(const float2*)(h2 + (size_t)s * 128 + c);
    a0 = fmaf(hv.x, w, a0);
    a1 = fmaf(hv.y, w, a1);
  }
  float inv = 1.0f / (wsum + 1e-16f);
  unsigned int bb = *(const unsigned int*)(b2 + c);
  float r0 = a0 * inv + bf2f(bb & 0xffff);
  float r1 = a1 * inv + bf2f(bb >> 16);
  if (flags[0]) {
    unsigned int o = (unsigned int)f2bf(r0) | ((unsigned int)f2bf(r1) << 16);
    *(unsigned int*)((unsigned short*)out + (size_t)n * 128 + c) = o;
  } else {
    *(float2*)((float*)out + (size_t)n * 128 + c) = make_float2(r0, r1);
  }
}

// ---------------------------------------------------------------------------
extern "C" void kernel_launch(void* const* d_in, const int* in_sizes, int n_in,
                              void* d_out, int out_size, void* d_ws,
                              size_t ws_size, hipStream_t stream) {
  const void* x      = d_in[0];
  const int*  ei     = (const int*)d_in[1];
  const void* W1     = d_in[2];
  const void* a_src1 = d_in[3];
  const void* a_dst1 = d_in[4];
  const void* b1     = d_in[5];
  const void* gamma  = d_in[6];
  const void* beta   = d_in[7];
  const void* W2     = d_in[8];
  const void* a_src2 = d_in[9];
  const void* a_dst2 = d_in[10];
  const void* b2     = d_in[11];

  const int N = in_sizes[0] / 128;            // 50000
  const int E = in_sizes[1] / 2;              // 150000
  const int MP = ((N + 127) / 128) * 128;     // 50048 (M padded for MFMA tiles)

  // ---- workspace layout (bytes) ----
  char* ws = (char*)d_ws;
  size_t off = 0;
  unsigned short* h1  = (unsigned short*)(ws + off); off += (size_t)MP * 1024 * 2;
  char* h1n_base = ws + off;
  unsigned short* h1n = (unsigned short*)h1n_base;   off += (size_t)MP * 1024 * 2;
  float* ssrc1 = (float*)(ws + off); off += (size_t)N * 8 * 4;
  float* sdst1 = (float*)(ws + off); off += (size_t)N * 8 * 4;
  int* offsets = (int*)(ws + off); off += ((size_t)(N + 1) * 4 + 63) & ~63ull;
  int* srcs    = (int*)(ws + off); off += (size_t)E * 4;
  unsigned short* W1t = (unsigned short*)(ws + off); off += 131072 * 2;  // [1024][128]
  unsigned short* W2t = (unsigned short*)(ws + off); off += 131072 * 2;  // [128][1024]
  unsigned short* as1c = (unsigned short*)(ws + off); off += 1024 * 2;
  unsigned short* ad1c = (unsigned short*)(ws + off); off += 1024 * 2;
  unsigned short* b1c  = (unsigned short*)(ws + off); off += 1024 * 2;
  unsigned short* gmc  = (unsigned short*)(ws + off); off += 1024 * 2;
  unsigned short* btc  = (unsigned short*)(ws + off); off += 1024 * 2;
  unsigned short* as2c = (unsigned short*)(ws + off); off += 128 * 2;
  unsigned short* ad2c = (unsigned short*)(ws + off); off += 128 * 2;
  unsigned short* b2c  = (unsigned short*)(ws + off); off += 128 * 2;
  float* bns1  = (float*)(ws + off); off += 1024 * 4;
  float* bns2  = (float*)(ws + off); off += 1024 * 4;
  float* scale = (float*)(ws + off); off += 1024 * 4;
  float* shift = (float*)(ws + off); off += 1024 * 4;
  int* flags   = (int*)(ws + off); off += 64;
  // Aliases into dead regions:
  // x_bf/eis/eid/cursor live in h1n's first 18 MB (dead before agg1 writes h1n;
  // h1n pad rows live at the END of the buffer — no overlap with these).
  unsigned short* x_bf = (unsigned short*)h1n_base;             // MP*128*2 = 12.8 MB
  int* eis    = (int*)(h1n_base + (16u << 20));
  int* eid    = eis + E;
  int* cursor = eid + E;
  // h2 (fp32 [MP][128] = 25.6 MB) aliases h1 (dead after agg1).
  float* h2    = (float*)h1;
  float* ssrc2 = ssrc1;
  float* sdst2 = sdst1;

  // ---- detection + canonicalization ----
  detect_kernel<<<1, 256, 0, stream>>>((const unsigned int*)x,
                                       (const unsigned int*)ei, E, flags);
  canon_x<<<(MP * 128 + 255) / 256, 256, 0, stream>>>(x, x_bf, N * 128,
                                                      MP * 128, flags);
  canon_w_t<<<(131072 + 255) / 256, 256, 0, stream>>>(W1, W1t, 128, 1024, flags);
  canon_w_t<<<(131072 + 255) / 256, 256, 0, stream>>>(W2, W2t, 1024, 128, flags);
  canon_params<<<8, 1024, 0, stream>>>(a_src1, a_dst1, b1, gamma, beta, a_src2,
                                       a_dst2, b2, as1c, ad1c, b1c, gmc, btc,
                                       as2c, ad2c, b2c, flags);
  canon_idx<<<(E + 255) / 256, 256, 0, stream>>>(ei, eis, eid, E, flags);

  // ---- zero init ----
  hipMemsetAsync(cursor, 0, (size_t)N * 4, stream);
  hipMemsetAsync(bns1, 0, 2048 * 4, stream);  // bns1+bns2 contiguous
  // h1n pad rows (read by GEMM2) — keep them finite:
  hipMemsetAsync((char*)h1n + (size_t)N * 1024 * 2, 0,
                 (size_t)(MP - N) * 1024 * 2, stream);

  // ---- CSR build (dst-sorted) ----
  count_dst<<<(E + 255) / 256, 256, 0, stream>>>(eid, E, cursor);
  scan_offsets<<<1, 1024, 0, stream>>>(cursor, offsets, N);
  scatter_src<<<(E + 255) / 256, 256, 0, stream>>>(eis, eid, E, cursor, srcs);

  // ---- Layer 1: h1 = x @ W1 (MFMA) ----
  {
    dim3 g(1024 / 128, MP / 128);
    gemm_mfma<128, false, true><<<g, 256, 0, stream>>>(
        x_bf, W1t, h1, MP, 1024, 128, nullptr, nullptr);
  }
  scores_bf16<<<(N * 8 + 3) / 4, 256, 0, stream>>>(h1, as1c, ad1c, ssrc1,
                                                   sdst1, N, 8);
  agg1_csr<<<N, 256, 0, stream>>>(offsets, srcs, h1, ssrc1, sdst1, b1c, h1n);

  bn_stats<<<(N + 255) / 256, 256, 0, stream>>>(h1n, bns1, bns2, N, 256);
  bn_finalize<<<1, 1024, 0, stream>>>(bns1, bns2, gmc, btc, scale, shift, N);

  // ---- Layer 2: h2 = ELU(BN(h1n)) @ W2 (MFMA, BN+ELU fused into A-load) ----
  {
    dim3 g(1, MP / 64);
    gemm_mfma<64, true, false><<<g, 256, 0, stream>>>(
        h1n, W2t, h2, MP, 128, 1024, scale, shift);
  }
  scores2_f32<<<(N + 3) / 4, 256, 0, stream>>>(h2, as2c, ad2c, ssrc2, sdst2, N);
  agg2_csr<<<N, 64, 0, stream>>>(offsets, srcs, h2, ssrc2, sdst2, b2c, d_out,
                                 flags);
}

// Round 6
// 525.109 us; speedup vs baseline: 1.6504x; 1.1757x over previous
//
#include <hip/hip_runtime.h>
#include <hip/hip_bf16.h>
#include <math.h>

#define NEG_SLOPE 0.2f
#define BN_EPS 1e-5f

typedef short bf16x8 __attribute__((ext_vector_type(8)));
typedef float f32x4 __attribute__((ext_vector_type(4)));

// ---- bf16 helpers (raw ushort payload) ------------------------------------
__device__ __forceinline__ float bf2f(unsigned short u) {
  union { unsigned int i; float f; } v;
  v.i = ((unsigned int)u) << 16;
  return v.f;
}
__device__ __forceinline__ unsigned short f2bf(float f) {
  union { unsigned int i; float f; } v;
  v.f = f;
  unsigned int i = v.i;
  unsigned int r = (i + 0x7fffu + ((i >> 16) & 1u)) >> 16;  // RNE
  return (unsigned short)r;
}

// ---------------------------------------------------------------------------
// Dtype detection: flags[0]=1 if floats are bf16; flags[1]=1 if idx int64.
// ---------------------------------------------------------------------------
__global__ __launch_bounds__(256) void detect_kernel(
    const unsigned int* __restrict__ xw, const unsigned int* __restrict__ eiw,
    int E, int* __restrict__ flags) {
  __shared__ int cnt[2];
  if (threadIdx.x < 2) cnt[threadIdx.x] = 0;
  __syncthreads();
  int t = threadIdx.x;
  int inrange = 0;
  for (int i = t; i < 2048; i += 256) {
    unsigned int e = (xw[i] >> 7) & 0xFFu;
    inrange += (e >= 100u && e <= 135u) ? 1 : 0;
  }
  atomicAdd(&cnt[0], inrange);
  int M = min(1024, E / 2);
  int zeros = 0;
  for (int i = t; i < M; i += 256) zeros += (eiw[2 * i + 1] == 0u) ? 1 : 0;
  atomicAdd(&cnt[1], zeros);
  __syncthreads();
  if (t == 0) {
    flags[0] = (cnt[0] > 1536) ? 1 : 0;
    flags[1] = (cnt[1] > M / 2) ? 1 : 0;
  }
}

// x -> bf16, zero-padded to n_total elements.
__global__ __launch_bounds__(256) void canon_x(
    const void* __restrict__ src, unsigned short* __restrict__ dst, int n_real,
    int n_total, const int* __restrict__ flags) {
  int i = blockIdx.x * 256 + threadIdx.x;
  if (i >= n_total) return;
  unsigned short v = 0;
  if (i < n_real)
    v = flags[0] ? ((const unsigned short*)src)[i]
                 : f2bf(((const float*)src)[i]);
  dst[i] = v;
}

// W [K][N] -> Wt [N][K] bf16.
__global__ __launch_bounds__(256) void canon_w_t(
    const void* __restrict__ src, unsigned short* __restrict__ dst, int Kdim,
    int Ndim, const int* __restrict__ flags) {
  int i = blockIdx.x * 256 + threadIdx.x;
  if (i >= Kdim * Ndim) return;
  int k = i / Ndim, n = i - k * Ndim;
  unsigned short v = flags[0] ? ((const unsigned short*)src)[i]
                              : f2bf(((const float*)src)[i]);
  dst[(size_t)n * Kdim + k] = v;
}

// All small param tensors in one launch: block b -> tensor b.
__global__ __launch_bounds__(1024) void canon_params(
    const void* s0, const void* s1, const void* s2, const void* s3,
    const void* s4, const void* s5, const void* s6, const void* s7,
    unsigned short* d0, unsigned short* d1, unsigned short* d2,
    unsigned short* d3, unsigned short* d4, unsigned short* d5,
    unsigned short* d6, unsigned short* d7, const int* __restrict__ flags) {
  int b = blockIdx.x, t = threadIdx.x;
  const void* s;
  unsigned short* d;
  int n;
  switch (b) {
    case 0: s = s0; d = d0; n = 1024; break;
    case 1: s = s1; d = d1; n = 1024; break;
    case 2: s = s2; d = d2; n = 1024; break;
    case 3: s = s3; d = d3; n = 1024; break;
    case 4: s = s4; d = d4; n = 1024; break;
    case 5: s = s5; d = d5; n = 128; break;
    case 6: s = s6; d = d6; n = 128; break;
    default: s = s7; d = d7; n = 128; break;
  }
  if (t < n)
    d[t] = flags[0] ? ((const unsigned short*)s)[t]
                    : f2bf(((const float*)s)[t]);
}

// edge_index -> int32 src[]/dst[].
__global__ __launch_bounds__(256) void canon_idx(
    const int* __restrict__ ei, int* __restrict__ eis, int* __restrict__ eid,
    int E, const int* __restrict__ flags) {
  int e = blockIdx.x * 256 + threadIdx.x;
  if (e >= E) return;
  if (flags[1]) {
    eis[e] = ei[2 * (size_t)e];
    eid[e] = ei[2 * (size_t)E + 2 * (size_t)e];
  } else {
    eis[e] = ei[e];
    eid[e] = ei[E + e];
  }
}

// ---------------------------------------------------------------------------
// MFMA GEMM: C[M,BNgrid*128] = A[M,K] @ Bt[N,K]^T.  A,Bt bf16 row-major.
// BM in {64,128}, BN=128, BK=32, 256 threads = 4 waves (2x2), wave tile
// (BM/2)x64 of 16x16x32 MFMAs.  M must be a multiple of BM (padded buffers).
// TRANSFORM_A: A' = ELU(A*scale[ch]+shift[ch]) applied during staging
// (fuses BatchNorm+ELU into GEMM2's A-load).
// ---------------------------------------------------------------------------
template <int BM, bool TRANSFORM_A, bool OUT_BF16>
__global__ __launch_bounds__(256) void gemm_mfma(
    const unsigned short* __restrict__ A, const unsigned short* __restrict__ Bt,
    void* __restrict__ Cv, int M, int N, int K,
    const float* __restrict__ scale, const float* __restrict__ shift) {
  constexpr int BK = 32;
  constexpr int LDA = BK + 8;
  __shared__ unsigned short As[BM * LDA];
  __shared__ unsigned short Bs[128 * LDA];

  const int m0 = blockIdx.y * BM;
  const int n0 = blockIdx.x * 128;
  const int tid = threadIdx.x;
  const int wid = tid >> 6;
  const int lane = tid & 63;
  const int q = lane >> 4;
  const int r = lane & 15;
  const int wm = (wid >> 1) * (BM / 2);
  const int wn = (wid & 1) * 64;

  constexpr int MI = BM / 32;
  f32x4 acc[MI][4] = {};

  for (int k0 = 0; k0 < K; k0 += BK) {
#pragma unroll
    for (int rd = 0; rd < BM / 64; ++rd) {
      int idx = rd * 2048 + tid * 8;
      int row = idx >> 5;
      int col = idx & 31;
      bf16x8 v = *(const bf16x8*)(A + (size_t)(m0 + row) * K + k0 + col);
      if (TRANSFORM_A) {
        union { bf16x8 v; unsigned short u[8]; } p;
        p.v = v;
#pragma unroll
        for (int j = 0; j < 8; ++j) {
          int ch = k0 + col + j;
          float f = bf2f(p.u[j]) * scale[ch] + shift[ch];
          f = f > 0.f ? f : expm1f(f);
          p.u[j] = f2bf(f);
        }
        v = p.v;
      }
      *(bf16x8*)(&As[row * LDA + col]) = v;
    }
#pragma unroll
    for (int rd = 0; rd < 2; ++rd) {
      int idx = rd * 2048 + tid * 8;
      int row = idx >> 5;
      int col = idx & 31;
      bf16x8 v = *(const bf16x8*)(Bt + (size_t)(n0 + row) * K + k0 + col);
      *(bf16x8*)(&Bs[row * LDA + col]) = v;
    }
    __syncthreads();

    bf16x8 af[MI], bfv[4];
#pragma unroll
    for (int mi = 0; mi < MI; ++mi)
      af[mi] = *(const bf16x8*)(&As[(wm + mi * 16 + r) * LDA + q * 8]);
#pragma unroll
    for (int ni = 0; ni < 4; ++ni)
      bfv[ni] = *(const bf16x8*)(&Bs[(wn + ni * 16 + r) * LDA + q * 8]);
#pragma unroll
    for (int mi = 0; mi < MI; ++mi)
#pragma unroll
      for (int ni = 0; ni < 4; ++ni)
        acc[mi][ni] = __builtin_amdgcn_mfma_f32_16x16x32_bf16(
            af[mi], bfv[ni], acc[mi][ni], 0, 0, 0);
    __syncthreads();
  }

#pragma unroll
  for (int mi = 0; mi < MI; ++mi) {
#pragma unroll
    for (int ni = 0; ni < 4; ++ni) {
#pragma unroll
      for (int i = 0; i < 4; ++i) {
        int row = m0 + wm + mi * 16 + q * 4 + i;
        int col = n0 + wn + ni * 16 + r;
        if (OUT_BF16)
          ((unsigned short*)Cv)[(size_t)row * N + col] = f2bf(acc[mi][ni][i]);
        else
          ((float*)Cv)[(size_t)row * N + col] = acc[mi][ni][i];
      }
    }
  }
}

// ---------------------------------------------------------------------------
// CSR build over dst — parallel 3-phase scan (replaces 109 µs 1-block scan).
// CHUNK = 2048 counts per block.
// ---------------------------------------------------------------------------
__global__ __launch_bounds__(256) void count_dst(const int* __restrict__ eid,
                                                 int E, int* __restrict__ cnt) {
  int e = blockIdx.x * 256 + threadIdx.x;
  if (e < E) atomicAdd(&cnt[eid[e]], 1);
}

// Phase 1: bsum[b] = sum of cnt[b*2048 .. b*2048+2048)
__global__ __launch_bounds__(256) void scan_p1(const int* __restrict__ cnt,
                                               int* __restrict__ bsum, int N) {
  __shared__ int sd[256];
  int b = blockIdx.x, t = threadIdx.x;
  int base = b * 2048;
  int s = 0;
  for (int i = t; i < 2048; i += 256) {
    int idx = base + i;
    if (idx < N) s += cnt[idx];
  }
  sd[t] = s;
  __syncthreads();
  for (int o = 128; o > 0; o >>= 1) {
    if (t < o) sd[t] += sd[t + o];
    __syncthreads();
  }
  if (t == 0) bsum[b] = sd[0];
}

// Phase 2: exclusive-scan bsum[nb] in place (nb <= 256), single block.
__global__ __launch_bounds__(256) void scan_p2(int* __restrict__ bsum, int nb) {
  __shared__ int sd[256];
  int t = threadIdx.x;
  int own = (t < nb) ? bsum[t] : 0;
  sd[t] = own;
  __syncthreads();
  for (int o = 1; o < 256; o <<= 1) {
    int v = (t >= o) ? sd[t - o] : 0;
    __syncthreads();
    sd[t] += v;
    __syncthreads();
  }
  if (t < nb) bsum[t] = sd[t] - own;  // exclusive
}

// Phase 3: block b writes offsets/cursor for its chunk; last block writes
// offsets[N]. Thread t handles 8 consecutive counts.
__global__ __launch_bounds__(256) void scan_p3(
    const int* __restrict__ cnt, const int* __restrict__ bsum,
    int* __restrict__ offsets, int* __restrict__ cursor, int N) {
  __shared__ int sd[256];
  int b = blockIdx.x, t = threadIdx.x;
  int base = b * 2048 + t * 8;
  int c[8];
  int ts = 0;
#pragma unroll
  for (int j = 0; j < 8; ++j) {
    int idx = base + j;
    c[j] = (idx < N) ? cnt[idx] : 0;
    ts += c[j];
  }
  sd[t] = ts;
  __syncthreads();
  for (int o = 1; o < 256; o <<= 1) {
    int v = (t >= o) ? sd[t - o] : 0;
    __syncthreads();
    sd[t] += v;
    __syncthreads();
  }
  int run = bsum[b] + sd[t] - ts;  // exclusive offset of this thread's chunk
#pragma unroll
  for (int j = 0; j < 8; ++j) {
    int idx = base + j;
    if (idx < N) {
      offsets[idx] = run;
      cursor[idx] = run;
      run += c[j];
    }
  }
  if (b == gridDim.x - 1 && t == 255) offsets[N] = bsum[b] + sd[255];
}

__global__ __launch_bounds__(256) void scatter_src(
    const int* __restrict__ eis, const int* __restrict__ eid, int E,
    int* __restrict__ cursor, int* __restrict__ srcs) {
  int e = blockIdx.x * 256 + threadIdx.x;
  if (e >= E) return;
  int pos = atomicAdd(&cursor[eid[e]], 1);
  srcs[pos] = eis[e];
}

// ---------------------------------------------------------------------------
// Scores: s[n,h] = dot(h[n,h,:], a[h,:]). One wave per (n,h); C=128.
// ---------------------------------------------------------------------------
__global__ __launch_bounds__(256) void scores_bf16(
    const unsigned short* __restrict__ hfeat,
    const unsigned short* __restrict__ a_src,
    const unsigned short* __restrict__ a_dst, float* __restrict__ s_src,
    float* __restrict__ s_dst, int N, int H) {
  int w = blockIdx.x * 4 + (threadIdx.x >> 6);
  int lane = threadIdx.x & 63;
  if (w >= N * H) return;
  int n = w / H;
  int hh = w - n * H;

  unsigned int hv =
      *(const unsigned int*)(hfeat + (size_t)n * H * 128 + hh * 128 + lane * 2);
  unsigned int av = *(const unsigned int*)(a_src + hh * 128 + lane * 2);
  unsigned int dv = *(const unsigned int*)(a_dst + hh * 128 + lane * 2);
  float h0 = bf2f(hv & 0xffff), h1 = bf2f(hv >> 16);
  float vs = h0 * bf2f(av & 0xffff) + h1 * bf2f(av >> 16);
  float vd = h0 * bf2f(dv & 0xffff) + h1 * bf2f(dv >> 16);
#pragma unroll
  for (int off = 32; off > 0; off >>= 1) {
    vs += __shfl_down(vs, off, 64);
    vd += __shfl_down(vd, off, 64);
  }
  if (lane == 0) {
    s_src[n * H + hh] = vs;
    s_dst[n * H + hh] = vd;
  }
}

// Layer-2 scores: h2 fp32, H=1.
__global__ __launch_bounds__(256) void scores2_f32(
    const float* __restrict__ h2, const unsigned short* __restrict__ a_src,
    const unsigned short* __restrict__ a_dst, float* __restrict__ s_src,
    float* __restrict__ s_dst, int N) {
  int w = blockIdx.x * 4 + (threadIdx.x >> 6);
  int lane = threadIdx.x & 63;
  if (w >= N) return;
  float2 hv = *(const float2*)(h2 + (size_t)w * 128 + lane * 2);
  unsigned int av = *(const unsigned int*)(a_src + lane * 2);
  unsigned int dv = *(const unsigned int*)(a_dst + lane * 2);
  float vs = hv.x * bf2f(av & 0xffff) + hv.y * bf2f(av >> 16);
  float vd = hv.x * bf2f(dv & 0xffff) + hv.y * bf2f(dv >> 16);
#pragma unroll
  for (int off = 32; off > 0; off >>= 1) {
    vs += __shfl_down(vs, off, 64);
    vd += __shfl_down(vd, off, 64);
  }
  if (lane == 0) {
    s_src[w] = vs;
    s_dst[w] = vd;
  }
}

// ---------------------------------------------------------------------------
// Layer-1 aggregation (CSR, block per dst node, 256 threads, 4 ch/thread).
// Writes h1n = raw agg/denom + b1 (pre-BN, bf16). BN+ELU applied in GEMM2.
// ---------------------------------------------------------------------------
__global__ __launch_bounds__(256) void agg1_csr(
    const int* __restrict__ offsets, const int* __restrict__ srcs,
    const unsigned short* __restrict__ h1, const float* __restrict__ ssrc,
    const float* __restrict__ sdst, const unsigned short* __restrict__ b1,
    unsigned short* __restrict__ h1n) {
  int n = blockIdx.x;
  int j = threadIdx.x;
  int c = j * 4;
  int h = c >> 7;
  float sd = sdst[n * 8 + h];
  int beg = offsets[n], end = offsets[n + 1];
  float a0 = 0.f, a1 = 0.f, a2 = 0.f, a3 = 0.f, wsum = 0.f;
  for (int p = beg; p < end; ++p) {
    int s = srcs[p];
    float v = ssrc[s * 8 + h] + sd;
    v = v > 0.f ? v : NEG_SLOPE * v;
    float w = expf(v);
    wsum += w;
    ushort4 u = *(const ushort4*)(h1 + (size_t)s * 1024 + c);
    a0 = fmaf(bf2f(u.x), w, a0);
    a1 = fmaf(bf2f(u.y), w, a1);
    a2 = fmaf(bf2f(u.z), w, a2);
    a3 = fmaf(bf2f(u.w), w, a3);
  }
  float inv = 1.0f / (wsum + 1e-16f);
  ushort4 bb = *(const ushort4*)(b1 + c);
  ushort4 o;
  o.x = f2bf(a0 * inv + bf2f(bb.x));
  o.y = f2bf(a1 * inv + bf2f(bb.y));
  o.z = f2bf(a2 * inv + bf2f(bb.z));
  o.w = f2bf(a3 * inv + bf2f(bb.w));
  *(ushort4*)(h1n + (size_t)n * 1024 + c) = o;
}

// ---------------------------------------------------------------------------
// BN partial sums over h1n (bf16, pre-BN values).
// ---------------------------------------------------------------------------
__global__ __launch_bounds__(256) void bn_stats(
    const unsigned short* __restrict__ h1n, float* __restrict__ bnsum,
    float* __restrict__ bnsumsq, int N, int rowsPerBlock) {
  int r0 = blockIdx.x * rowsPerBlock;
  int r1 = min(r0 + rowsPerBlock, N);
  int c = threadIdx.x * 4;
  float s0 = 0, s1 = 0, s2 = 0, s3 = 0;
  float q0 = 0, q1 = 0, q2 = 0, q3 = 0;
  for (int r = r0; r < r1; ++r) {
    ushort4 u = *(const ushort4*)(h1n + (size_t)r * 1024 + c);
    float v0 = bf2f(u.x), v1 = bf2f(u.y), v2 = bf2f(u.z), v3 = bf2f(u.w);
    s0 += v0; s1 += v1; s2 += v2; s3 += v3;
    q0 += v0 * v0; q1 += v1 * v1; q2 += v2 * v2; q3 += v3 * v3;
  }
  atomicAdd(&bnsum[c + 0], s0);
  atomicAdd(&bnsum[c + 1], s1);
  atomicAdd(&bnsum[c + 2], s2);
  atomicAdd(&bnsum[c + 3], s3);
  atomicAdd(&bnsumsq[c + 0], q0);
  atomicAdd(&bnsumsq[c + 1], q1);
  atomicAdd(&bnsumsq[c + 2], q2);
  atomicAdd(&bnsumsq[c + 3], q3);
}

__global__ __launch_bounds__(1024) void bn_finalize(
    const float* __restrict__ bnsum, const float* __restrict__ bnsumsq,
    const unsigned short* __restrict__ gamma,
    const unsigned short* __restrict__ beta, float* __restrict__ scale,
    float* __restrict__ shift, int N) {
  int j = threadIdx.x;
  float inv_n = 1.0f / (float)N;
  float mu = bnsum[j] * inv_n;
  float var = bnsumsq[j] * inv_n - mu * mu;
  float sc = bf2f(gamma[j]) * rsqrtf(var + BN_EPS);
  scale[j] = sc;
  shift[j] = bf2f(beta[j]) - mu * sc;
}

// ---------------------------------------------------------------------------
// Layer-2 aggregation (CSR, one wave per dst, 2 ch/lane).
// ---------------------------------------------------------------------------
__global__ __launch_bounds__(64) void agg2_csr(
    const int* __restrict__ offsets, const int* __restrict__ srcs,
    const float* __restrict__ h2, const float* __restrict__ ssrc,
    const float* __restrict__ sdst, const unsigned short* __restrict__ b2,
    void* __restrict__ out, const int* __restrict__ flags) {
  int n = blockIdx.x;
  int lane = threadIdx.x;
  int c = lane * 2;
  float sd = sdst[n];
  int beg = offsets[n], end = offsets[n + 1];
  float a0 = 0.f, a1 = 0.f, wsum = 0.f;
  for (int p = beg; p < end; ++p) {
    int s = srcs[p];
    float v = ssrc[s] + sd;
    v = v > 0.f ? v : NEG_SLOPE * v;
    float w = expf(v);
    wsum += w;
    float2 hv = *(const float2*)(h2 + (size_t)s * 128 + c);
    a0 = fmaf(hv.x, w, a0);
    a1 = fmaf(hv.y, w, a1);
  }
  float inv = 1.0f / (wsum + 1e-16f);
  unsigned int bb = *(const unsigned int*)(b2 + c);
  float r0 = a0 * inv + bf2f(bb & 0xffff);
  float r1 = a1 * inv + bf2f(bb >> 16);
  if (flags[0]) {
    unsigned int o = (unsigned int)f2bf(r0) | ((unsigned int)f2bf(r1) << 16);
    *(unsigned int*)((unsigned short*)out + (size_t)n * 128 + c) = o;
  } else {
    *(float2*)((float*)out + (size_t)n * 128 + c) = make_float2(r0, r1);
  }
}

// ---------------------------------------------------------------------------
extern "C" void kernel_launch(void* const* d_in, const int* in_sizes, int n_in,
                              void* d_out, int out_size, void* d_ws,
                              size_t ws_size, hipStream_t stream) {
  const void* x      = d_in[0];
  const int*  ei     = (const int*)d_in[1];
  const void* W1     = d_in[2];
  const void* a_src1 = d_in[3];
  const void* a_dst1 = d_in[4];
  const void* b1     = d_in[5];
  const void* gamma  = d_in[6];
  const void* beta   = d_in[7];
  const void* W2     = d_in[8];
  const void* a_src2 = d_in[9];
  const void* a_dst2 = d_in[10];
  const void* b2     = d_in[11];

  const int N = in_sizes[0] / 128;            // 50000
  const int E = in_sizes[1] / 2;              // 150000
  const int MP = ((N + 127) / 128) * 128;     // 50048
  const int NB = (N + 2047) / 2048;           // scan chunks (25)

  // ---- workspace layout (bytes) ----
  char* ws = (char*)d_ws;
  size_t off = 0;
  unsigned short* h1  = (unsigned short*)(ws + off); off += (size_t)MP * 1024 * 2;
  char* h1n_base = ws + off;
  unsigned short* h1n = (unsigned short*)h1n_base;   off += (size_t)MP * 1024 * 2;
  float* ssrc1 = (float*)(ws + off); off += (size_t)N * 8 * 4;
  float* sdst1 = (float*)(ws + off); off += (size_t)N * 8 * 4;
  int* offsets = (int*)(ws + off); off += ((size_t)(N + 1) * 4 + 63) & ~63ull;
  int* srcs    = (int*)(ws + off); off += (size_t)E * 4;
  unsigned short* W1t = (unsigned short*)(ws + off); off += 131072 * 2;
  unsigned short* W2t = (unsigned short*)(ws + off); off += 131072 * 2;
  unsigned short* as1c = (unsigned short*)(ws + off); off += 1024 * 2;
  unsigned short* ad1c = (unsigned short*)(ws + off); off += 1024 * 2;
  unsigned short* b1c  = (unsigned short*)(ws + off); off += 1024 * 2;
  unsigned short* gmc  = (unsigned short*)(ws + off); off += 1024 * 2;
  unsigned short* btc  = (unsigned short*)(ws + off); off += 1024 * 2;
  unsigned short* as2c = (unsigned short*)(ws + off); off += 128 * 2;
  unsigned short* ad2c = (unsigned short*)(ws + off); off += 128 * 2;
  unsigned short* b2c  = (unsigned short*)(ws + off); off += 128 * 2;
  float* bns1  = (float*)(ws + off); off += 1024 * 4;
  float* bns2  = (float*)(ws + off); off += 1024 * 4;
  float* scale = (float*)(ws + off); off += 1024 * 4;
  float* shift = (float*)(ws + off); off += 1024 * 4;
  int* bsum    = (int*)(ws + off); off += 256 * 4;
  int* flags   = (int*)(ws + off); off += 64;
  // Aliases into dead regions (h1n's first 18 MB; dead before agg1 writes h1n;
  // pad rows live at the END of h1n — no overlap).
  unsigned short* x_bf = (unsigned short*)h1n_base;
  int* eis    = (int*)(h1n_base + (16u << 20));
  int* eid    = eis + E;
  int* cnt    = eid + E;      // dst counts
  int* cursor = cnt + N;      // scatter cursors
  // h2 (fp32 [MP][128] = 25.6 MB) aliases h1 (dead after agg1).
  float* h2    = (float*)h1;
  float* ssrc2 = ssrc1;
  float* sdst2 = sdst1;

  // ---- detection + canonicalization ----
  detect_kernel<<<1, 256, 0, stream>>>((const unsigned int*)x,
                                       (const unsigned int*)ei, E, flags);
  canon_x<<<(MP * 128 + 255) / 256, 256, 0, stream>>>(x, x_bf, N * 128,
                                                      MP * 128, flags);
  canon_w_t<<<(131072 + 255) / 256, 256, 0, stream>>>(W1, W1t, 128, 1024, flags);
  canon_w_t<<<(131072 + 255) / 256, 256, 0, stream>>>(W2, W2t, 1024, 128, flags);
  canon_params<<<8, 1024, 0, stream>>>(a_src1, a_dst1, b1, gamma, beta, a_src2,
                                       a_dst2, b2, as1c, ad1c, b1c, gmc, btc,
                                       as2c, ad2c, b2c, flags);
  canon_idx<<<(E + 255) / 256, 256, 0, stream>>>(ei, eis, eid, E, flags);

  // ---- zero init ----
  hipMemsetAsync(cnt, 0, (size_t)N * 4, stream);
  hipMemsetAsync(bns1, 0, 2048 * 4, stream);  // bns1+bns2 contiguous
  hipMemsetAsync((char*)h1n + (size_t)N * 1024 * 2, 0,
                 (size_t)(MP - N) * 1024 * 2, stream);

  // ---- CSR build (dst-sorted), parallel scan ----
  count_dst<<<(E + 255) / 256, 256, 0, stream>>>(eid, E, cnt);
  scan_p1<<<NB, 256, 0, stream>>>(cnt, bsum, N);
  scan_p2<<<1, 256, 0, stream>>>(bsum, NB);
  scan_p3<<<NB, 256, 0, stream>>>(cnt, bsum, offsets, cursor, N);
  scatter_src<<<(E + 255) / 256, 256, 0, stream>>>(eis, eid, E, cursor, srcs);

  // ---- Layer 1: h1 = x @ W1 (MFMA) ----
  {
    dim3 g(1024 / 128, MP / 128);
    gemm_mfma<128, false, true><<<g, 256, 0, stream>>>(
        x_bf, W1t, h1, MP, 1024, 128, nullptr, nullptr);
  }
  scores_bf16<<<(N * 8 + 3) / 4, 256, 0, stream>>>(h1, as1c, ad1c, ssrc1,
                                                   sdst1, N, 8);
  agg1_csr<<<N, 256, 0, stream>>>(offsets, srcs, h1, ssrc1, sdst1, b1c, h1n);

  bn_stats<<<(N + 255) / 256, 256, 0, stream>>>(h1n, bns1, bns2, N, 256);
  bn_finalize<<<1, 1024, 0, stream>>>(bns1, bns2, gmc, btc, scale, shift, N);

  // ---- Layer 2: h2 = ELU(BN(h1n)) @ W2 (MFMA, BN+ELU fused into A-load) ----
  {
    dim3 g(1, MP / 64);
    gemm_mfma<64, true, false><<<g, 256, 0, stream>>>(
        h1n, W2t, h2, MP, 128, 1024, scale, shift);
  }
  scores2_f32<<<(N + 3) / 4, 256, 0, stream>>>(h2, as2c, ad2c, ssrc2, sdst2, N);
  agg2_csr<<<N, 64, 0, stream>>>(offsets, srcs, h2, ssrc2, sdst2, b2c, d_out,
                                 flags);
}